// Round 9
// baseline (166.432 us; speedup 1.0000x reference)
//
#include <hip/hip_runtime.h>
#include <hip/hip_cooperative_groups.h>

// YOLOv2 post-process, ONE cooperative dispatch, no memset, no global atomics.
// score = sigm(obj)*sigm(cls), both < 1 => score>=T needs obj>=logit(T) AND
// cls>=logit(T); logit(0.86)=1.8153 > PRE_T=1.80 (prefilter skips ~97.4% of
// the 80MB cls read). All 980 blocks scan into DETERMINISTIC per-block slots
// (bcnt written unconditionally -> no init, no stale replay state), then
// grid.sync() (device-scope barrier: cross-XCD coherent), then block 0 runs
// the wave-parallel tail: slot compaction -> fhist refine (wave suffix scan)
// -> exact rank (score desc, idx asc) -> decode -> ballot IoU masks ->
// register/shfl greedy NMS. Rescue (slot>64 / total<100 / total>2048):
// exact one-block rescan — never taken on this data, correctness backstop.
// Outputs (float32 flat, 700): bboxes[400] | scores[100] | labels[100] | keep[100]

namespace cg = cooperative_groups;

#define KTOP    100
#define CAPL    2048u          // LDS candidate cap (typical count ~1100)
#define SLOT    64u
#define NBLK    980u
#define SELN    512
#define NQ      250880u        // anchors/4; grid covers exactly (980*256)
#define THRF    0.86f
#define PRE_T   1.80f          // sigm(1.80)=0.8581 < 0.86
#define CONF    0.01f
#define NMS_T   0.5f
#define STRIDEF 32.0f
#define COFF    1000000.0f

typedef unsigned long long u64;
typedef unsigned u32;

__device__ __forceinline__ float sigm(float x) {
  return __builtin_amdgcn_rcpf(1.0f + __builtin_amdgcn_exp2f(-1.442695040888963f * x));
}
__device__ __forceinline__ float fexp(float x) {
  return __builtin_amdgcn_exp2f(1.442695040888963f * x);
}

// ws: [0 .. 501760) cand u64[NBLK*SLOT]; [501760 .. 505680) bcnt u32[NBLK]

__global__ void __launch_bounds__(256, 4) k_fused(const float* __restrict__ obj,
    const float* __restrict__ cls, const float* __restrict__ reg,
    const float* __restrict__ anch, u64* __restrict__ cand,
    u32* __restrict__ bcnt, float* __restrict__ out) {
  __shared__ u64 lkey[SLOT];                  // scan collect
  __shared__ u64 ckey[CAPL];                  // 16 KiB compacted candidates
  __shared__ u32 rhist[2048];                 // rescue only
  __shared__ u64 selk[SELN];
  __shared__ u32 fhist[512];
  __shared__ u32 lcnt, ccnt, ovfs, scnt, bstar_s, nsel_s, rcnt;
  __shared__ float sc[KTOP];
  __shared__ u32 sid[KTOP];
  __shared__ float bx[KTOP][4];
  __shared__ float4 obF[KTOP];
  __shared__ u64 suplo[KTOP], suphi[KTOP], keepm[2];
  const int tid = threadIdx.x;
  const int lane = tid & 63;

  if (tid == 0) lcnt = 0u;
  __syncthreads();

  // ================= SCAN (all 980 blocks) =================
  {
    u32 q = blockIdx.x * 256u + (u32)tid;          // q < NQ (grid exact)
    float4 o4 = ((const float4*)obj)[q];
    float ov[4] = {o4.x, o4.y, o4.z, o4.w};
#pragma unroll
    for (int k = 0; k < 4; ++k) {
      if (ov[k] < PRE_T) continue;                 // 3.6% pass
      u32 a = q * 4u + (u32)k;
      float so = sigm(ov[k]);
      const float4* cp = (const float4*)(cls + (size_t)a * 20u);
      float4 c0 = cp[0], c1 = cp[1], c2 = cp[2], c3 = cp[3], c4 = cp[4];
      float cc[20] = {c0.x, c0.y, c0.z, c0.w, c1.x, c1.y, c1.z, c1.w,
                      c2.x, c2.y, c2.z, c2.w, c3.x, c3.y, c3.z, c3.w,
                      c4.x, c4.y, c4.z, c4.w};
#pragma unroll
      for (int j = 0; j < 20; ++j) {               // fully unrolled: static idx
        if (cc[j] >= PRE_T) {
          float s = so * sigm(cc[j]);
          if (s >= THRF) {
            u32 p = atomicAdd(&lcnt, 1u);          // LDS atomic only
            u32 idx = a * 20u + (u32)j;
            if (p < SLOT)
              lkey[p] = ((u64)__float_as_uint(s) << 32) | (u64)(0xFFFFFFFFu - idx);
          }
        }
      }
    }
    __syncthreads();
    u32 n = lcnt > SLOT ? SLOT : lcnt;
    for (u32 t = (u32)tid; t < n; t += 256u)
      cand[blockIdx.x * SLOT + t] = lkey[t];       // deterministic slot
    if (tid == 0) bcnt[blockIdx.x] = lcnt;         // uncapped: >SLOT => rescue
  }

  cg::this_grid().sync();                          // device-scope barrier
  if (blockIdx.x != 0) return;

  // ================= TAIL (block 0 only, 256 threads) =================
  if (tid == 0) { ccnt = 0u; ovfs = 0u; rcnt = 0u; scnt = 0u; }
  if (tid < KTOP) { sc[tid] = 0.0f; sid[tid] = 0u; }
  for (int i = tid; i < 512; i += 256) fhist[i] = 0u;
  __syncthreads();

  // ---- slot compaction into LDS (order-free; key carries tie-break) ----
  for (int r = 0; r < 4; ++r) {
    int b = tid + 256 * r;
    u32 c = (b < (int)NBLK) ? bcnt[b] : 0u;
    if (c > SLOT) atomicOr(&ovfs, 1u);
    u32 s = c > SLOT ? SLOT : c;
    if (s) {
      u32 base = atomicAdd(&ccnt, s);
      if (base + s > CAPL) atomicOr(&ovfs, 1u);
      for (u32 i = 0; i < s; ++i)
        if (base + i < CAPL) ckey[base + i] = cand[(u32)b * SLOT + i];
    }
  }
  __syncthreads();
  u32 count = ccnt > CAPL ? CAPL : ccnt;

  if (count < (u32)KTOP || ovfs) {
    // ---- rescue: exact one-block histogram rescan (never taken) ----
    for (int i = tid; i < 2048; i += 256) rhist[i] = 0u;
    __syncthreads();
    for (u32 qq = (u32)tid; qq < NQ; qq += 256u) {
      float4 oo = ((const float4*)obj)[qq];
      float o2[4] = {oo.x, oo.y, oo.z, oo.w};
      for (int k = 0; k < 4; ++k) {
        float so = sigm(o2[k]);
        u32 a = qq * 4u + (u32)k;
        const float4* cp = (const float4*)(cls + (size_t)a * 20u);
        for (int v = 0; v < 5; ++v) {
          float4 cv = cp[v];
          float cc[4] = {cv.x, cv.y, cv.z, cv.w};
          for (int j = 0; j < 4; ++j)
            atomicAdd(&rhist[__float_as_uint(so * sigm(cc[j])) >> 19], 1u);
        }
      }
    }
    __syncthreads();
    if (tid == 0) {
      u32 cum = 0; int b = 2047;
      for (; b >= 0; --b) { cum += rhist[b]; if (cum >= (u32)KTOP) break; }
      bstar_s = (b < 0) ? 0u : (u32)b;
    }
    __syncthreads();
    u32 rb = bstar_s;
    for (u32 qq = (u32)tid; qq < NQ; qq += 256u) {
      float4 oo = ((const float4*)obj)[qq];
      float o2[4] = {oo.x, oo.y, oo.z, oo.w};
      for (int k = 0; k < 4; ++k) {
        float so = sigm(o2[k]);
        u32 a = qq * 4u + (u32)k;
        const float4* cp = (const float4*)(cls + (size_t)a * 20u);
        for (int v = 0; v < 5; ++v) {
          float4 cv = cp[v];
          float cc[4] = {cv.x, cv.y, cv.z, cv.w};
          for (int j = 0; j < 4; ++j) {
            float sct = so * sigm(cc[j]);
            if ((__float_as_uint(sct) >> 19) >= rb) {
              u32 p = atomicAdd(&rcnt, 1u);
              u32 idx = a * 20u + (u32)(v * 4 + j);
              if (p < CAPL)
                ckey[p] = ((u64)__float_as_uint(sct) << 32) | (u64)(0xFFFFFFFFu - idx);
            }
          }
        }
      }
    }
    __syncthreads();
    count = rcnt > CAPL ? CAPL : rcnt;
  }

  // ---- fine histogram: bin=(bits>>14)-64512 exact+monotone on [0.5,1) ----
  for (u32 t = (u32)tid; t < count; t += 256u) {
    int bin = (int)((u32)(ckey[t] >> 32) >> 14) - 64512;
    bin = bin < 0 ? 0 : (bin > 511 ? 511 : bin);
    atomicAdd(&fhist[bin], 1u);
  }
  __syncthreads();

  // ---- bstar via wave-0 suffix scan ----
  if (tid < 64) {
    u32 b[8];
#pragma unroll
    for (int i = 0; i < 8; ++i) b[i] = fhist[lane * 8 + i];
    u32 seg = b[0] + b[1] + b[2] + b[3] + b[4] + b[5] + b[6] + b[7];
    u32 suf = seg;
#pragma unroll
    for (int d = 1; d < 64; d <<= 1) {
      u32 up = __shfl_down(suf, d);
      if (lane + d < 64) suf += up;
    }
    u64 mask = __ballot(suf >= (u32)KTOP);
    if (mask == 0ull) {
      if (lane == 0) { bstar_s = 0u; nsel_s = count; }
    } else {
      int lstar = 63 - __builtin_clzll(mask);
      int src = lstar < 63 ? lstar + 1 : 63;
      u32 cumAbove = __shfl(suf, src);
      if (lstar == 63) cumAbove = 0u;
      if (lane == lstar) {
        u32 cc2 = cumAbove; int found = 0; u32 ns = count; u32 bs = 0u;
#pragma unroll
        for (int i = 7; i >= 0; --i) {
          cc2 += b[i];
          if (!found && cc2 >= (u32)KTOP) { found = 1; bs = (u32)(lane * 8 + i); ns = cc2; }
        }
        bstar_s = bs; nsel_s = ns;
      }
    }
  }
  __syncthreads();
  const u32 bstar = bstar_s;
  const bool small = (nsel_s <= (u32)SELN);

  // ---- compact survivors (typical ~110) ----
  if (small) {
    for (u32 t = (u32)tid; t < count; t += 256u) {
      u64 k = ckey[t];
      int bin = (int)((u32)(k >> 32) >> 14) - 64512;
      bin = bin < 0 ? 0 : (bin > 511 ? 511 : bin);
      if ((u32)bin >= bstar) {
        u32 p = atomicAdd(&scnt, 1u);
        if (p < (u32)SELN) selk[p] = k;
      }
    }
  }
  __syncthreads();

  if (small) {
    u32 nn = scnt > (u32)SELN ? (u32)SELN : scnt;
    for (u32 t = (u32)tid; t < nn; t += 256u) {
      u64 k = selk[t];
      u32 rank = 0;
      for (u32 j = 0; j < nn; ++j) rank += (selk[j] > k) ? 1u : 0u;
      if (rank < (u32)KTOP) {
        sc[rank]  = __uint_as_float((u32)(k >> 32));
        sid[rank] = 0xFFFFFFFFu - (u32)(k & 0xFFFFFFFFull);
      }
    }
  } else {  // pathological fallback: exact rank over full LDS set (never taken)
    for (u32 t = (u32)tid; t < count; t += 256u) {
      u64 k = ckey[t];
      u32 rank = 0;
      for (u32 j = 0; j < count; ++j) rank += (ckey[j] > k) ? 1u : 0u;
      if (rank < (u32)KTOP) {
        sc[rank]  = __uint_as_float((u32)(k >> 32));
        sid[rank] = 0xFFFFFFFFu - (u32)(k & 0xFFFFFFFFull);
      }
    }
  }
  __syncthreads();

  // ---- decode top-100 ----
  if (tid < KTOP) {
    u32 idx = sid[tid];
    u32 a = idx / 20u, lab = idx % 20u;
    float4 r  = ((const float4*)reg)[a];
    float4 an = ((const float4*)anch)[a];
    float cx = (sigm(r.x) + an.x) * STRIDEF;
    float cy = (sigm(r.y) + an.y) * STRIDEF;
    float w  = fexp(r.z) * an.z;
    float h  = fexp(r.w) * an.w;
    float x1 = cx - 0.5f * w, y1 = cy - 0.5f * h;
    float x2 = cx + 0.5f * w, y2 = cy + 0.5f * h;
    bx[tid][0] = x1; bx[tid][1] = y1; bx[tid][2] = x2; bx[tid][3] = y2;
    float off = (float)lab * COFF;
    obF[tid] = make_float4(x1 + off, y1 + off, x2 + off, y2 + off);
  }
  __syncthreads();

  // ---- sup masks via ballot: one b128 LDS read per i, unroll 4 ----
  if (tid < 128) {
    int w = tid >> 6;
    int j = w * 64 + lane;
    bool jv = j < KTOP;
    float4 bj = jv ? obF[j] : make_float4(0.f, 0.f, 0.f, 0.f);
    float aj = (bj.z - bj.x) * (bj.w - bj.y);
#pragma unroll 4
    for (int i = 0; i < KTOP; ++i) {
      float4 bi = obF[i];
      float ai = (bi.z - bi.x) * (bi.w - bi.y);
      float xx1 = fmaxf(bi.x, bj.x), yy1 = fmaxf(bi.y, bj.y);
      float xx2 = fminf(bi.z, bj.z), yy2 = fminf(bi.w, bj.w);
      float ww = fmaxf(1e-10f, xx2 - xx1), hh = fmaxf(1e-10f, yy2 - yy1);
      float inter = ww * hh;
      float iou = inter / (ai + aj - inter);
      u64 m = __ballot(jv && (j > i) && (iou > NMS_T));
      if (lane == 0) { if (w == 0) suplo[i] = m; else suphi[i] = m; }
    }
  }
  __syncthreads();

  // ---- greedy NMS: rows in wave-0 registers, unrolled shfl, uniform ops ----
  if (tid < 64) {
    u64 rAlo = suplo[lane],                rAhi = suphi[lane];
    u64 rBlo = lane < 36 ? suplo[64 + lane] : 0ull;
    u64 rBhi = lane < 36 ? suphi[64 + lane] : 0ull;
    u64 k0 = __ballot(sc[lane] > CONF);
    u64 k1 = __ballot(lane < 36 && sc[64 + lane] > CONF);
#pragma unroll
    for (int i = 0; i < 64; ++i) {
      u64 s0 = __shfl(rAlo, i), s1 = __shfl(rAhi, i);
      if ((k0 >> i) & 1ull) { k0 &= ~s0; k1 &= ~s1; }
    }
#pragma unroll
    for (int i = 0; i < 36; ++i) {
      u64 s0 = __shfl(rBlo, i), s1 = __shfl(rBhi, i);
      if ((k1 >> i) & 1ull) { k0 &= ~s0; k1 &= ~s1; }
    }
    if (lane == 0) { keepm[0] = k0; keepm[1] = k1; }
  }
  __syncthreads();

  if (tid < KTOP) {
    out[tid * 4 + 0] = bx[tid][0];
    out[tid * 4 + 1] = bx[tid][1];
    out[tid * 4 + 2] = bx[tid][2];
    out[tid * 4 + 3] = bx[tid][3];
    out[400 + tid] = sc[tid];
    out[500 + tid] = (float)(sid[tid] % 20u);
    bool kp = (tid < 64) ? ((keepm[0] >> tid) & 1ull)
                         : ((keepm[1] >> (tid - 64)) & 1ull);
    out[600 + tid] = kp ? 1.0f : 0.0f;
  }
}

extern "C" void kernel_launch(void* const* d_in, const int* in_sizes, int n_in,
                              void* d_out, int out_size, void* d_ws, size_t ws_size,
                              hipStream_t stream) {
  (void)in_sizes; (void)n_in; (void)out_size; (void)ws_size;
  const float* obj  = (const float*)d_in[0];
  const float* cls  = (const float*)d_in[1];
  const float* reg  = (const float*)d_in[2];
  const float* anch = (const float*)d_in[3];
  float* out = (float*)d_out;

  u64* cand = (u64*)d_ws;
  u32* bcnt = (u32*)((char*)d_ws + (size_t)NBLK * SLOT * 8u);

  void* args[] = {(void*)&obj, (void*)&cls, (void*)&reg, (void*)&anch,
                  (void*)&cand, (void*)&bcnt, (void*)&out};
  hipLaunchCooperativeKernel((const void*)k_fused, dim3(NBLK), dim3(256),
                             args, 0, stream);
}

// Round 10
// 59.762 us; speedup vs baseline: 2.7849x; 2.7849x over previous
//
#include <hip/hip_runtime.h>

// YOLOv2 post-process, ONE plain dispatch, no memset, no grid.sync.
// score = sigm(obj)*sigm(cls), both < 1 => score>=T needs obj>=logit(T) AND
// cls>=logit(T); logit(0.86)=1.8153 > PRE_T=1.80 (prefilter skips ~97.4% of
// the 80MB cls read). All 980 blocks scan; candidates >= 0.86 are published to
// DETERMINISTIC per-block slots via device-scope atomicExch (coherent point;
// no fences needed: __syncthreads() drains vmcnt before tid0's atomicInc).
// Completion counting via module-global g_done with atomicInc(.., NBLK-1):
// self-wraps to 0 each call (deterministic across graph replays, immune to
// d_ws poison). The completion-order-LAST block runs the wave-parallel tail,
// reading cross-block data with RMW loads (r4-validated cross-XCD pattern):
// slot compaction -> fhist refine (wave suffix scan) -> exact rank (score
// desc, idx asc) -> decode -> ballot IoU masks -> register/shfl greedy NMS.
// Rescue (slot>64 / total<100 / total>2048): exact one-block rescan — never
// taken on this data, correctness backstop only.
// Outputs (float32 flat, 700): bboxes[400] | scores[100] | labels[100] | keep[100]

#define KTOP    100
#define CAPL    2048u          // LDS candidate cap (typical count ~1100)
#define SLOT    64u
#define NBLK    980u
#define SELN    512
#define NQ      250880u        // anchors/4; grid covers exactly (980*256)
#define THRF    0.86f
#define PRE_T   1.80f          // sigm(1.80)=0.8581 < 0.86
#define CONF    0.01f
#define NMS_T   0.5f
#define STRIDEF 32.0f
#define COFF    1000000.0f

typedef unsigned long long u64;
typedef unsigned u32;

__device__ u32 g_done = 0;     // module global: 0 at load, self-restoring

__device__ __forceinline__ float sigm(float x) {
  return __builtin_amdgcn_rcpf(1.0f + __builtin_amdgcn_exp2f(-1.442695040888963f * x));
}
__device__ __forceinline__ float fexp(float x) {
  return __builtin_amdgcn_exp2f(1.442695040888963f * x);
}

// ws: [0 .. 501760) cand u64[NBLK*SLOT]; [501760 .. 505680) bcnt u32[NBLK]

__global__ void __launch_bounds__(256) k_fused(const float* __restrict__ obj,
    const float* __restrict__ cls, const float* __restrict__ reg,
    const float* __restrict__ anch, u64* __restrict__ cand,
    u32* __restrict__ bcnt, float* __restrict__ out) {
  __shared__ u64 lkey[SLOT];
  __shared__ u64 ckey[CAPL];                  // 16 KiB compacted candidates
  __shared__ u32 rhist[2048];                 // rescue only
  __shared__ u64 selk[SELN];
  __shared__ u32 fhist[512];
  __shared__ u32 lcnt, islast, ccnt, ovfs, scnt, bstar_s, nsel_s, rcnt;
  __shared__ float sc[KTOP];
  __shared__ u32 sid[KTOP];
  __shared__ float bx[KTOP][4];
  __shared__ float4 obF[KTOP];
  __shared__ u64 suplo[KTOP], suphi[KTOP], keepm[2];
  const int tid = threadIdx.x;
  const int lane = tid & 63;

  if (tid == 0) lcnt = 0u;
  __syncthreads();

  // ================= SCAN (all 980 blocks) =================
  {
    u32 q = blockIdx.x * 256u + (u32)tid;          // q < NQ (grid exact)
    float4 o4 = ((const float4*)obj)[q];
    float ov[4] = {o4.x, o4.y, o4.z, o4.w};
#pragma unroll
    for (int k = 0; k < 4; ++k) {
      if (ov[k] < PRE_T) continue;                 // 3.6% pass
      u32 a = q * 4u + (u32)k;
      float so = sigm(ov[k]);
      const float4* cp = (const float4*)(cls + (size_t)a * 20u);
      float4 c0 = cp[0], c1 = cp[1], c2 = cp[2], c3 = cp[3], c4 = cp[4];
      float cc[20] = {c0.x, c0.y, c0.z, c0.w, c1.x, c1.y, c1.z, c1.w,
                      c2.x, c2.y, c2.z, c2.w, c3.x, c3.y, c3.z, c3.w,
                      c4.x, c4.y, c4.z, c4.w};
#pragma unroll
      for (int j = 0; j < 20; ++j) {               // fully unrolled: static idx
        if (cc[j] >= PRE_T) {
          float s = so * sigm(cc[j]);
          if (s >= THRF) {
            u32 p = atomicAdd(&lcnt, 1u);          // LDS atomic only
            u32 idx = a * 20u + (u32)j;
            if (p < SLOT)
              lkey[p] = ((u64)__float_as_uint(s) << 32) | (u64)(0xFFFFFFFFu - idx);
          }
        }
      }
    }
    __syncthreads();
    // publish via device-scope RMW (coherent point; no fence needed)
    u32 n = lcnt > SLOT ? SLOT : lcnt;
    for (u32 t = (u32)tid; t < n; t += 256u)
      atomicExch(&cand[blockIdx.x * SLOT + t], lkey[t]);
    if (tid == 0) atomicExch(&bcnt[blockIdx.x], lcnt);
    __syncthreads();                               // drains vmcnt (all publishes done)
    if (tid == 0) {
      u32 old = atomicInc(&g_done, NBLK - 1u);     // wraps to 0 on 980th inc
      islast = (old == NBLK - 1u) ? 1u : 0u;
    }
    __syncthreads();
    if (!islast) return;
  }

  // ================= TAIL (completion-order-last block) =================
  if (tid == 0) { ccnt = 0u; ovfs = 0u; rcnt = 0u; scnt = 0u; }
  if (tid < KTOP) { sc[tid] = 0.0f; sid[tid] = 0u; }
  for (int i = tid; i < 512; i += 256) fhist[i] = 0u;
  __syncthreads();

  // ---- slot compaction into LDS via RMW reads (order-free; key = tie-break) ----
  for (int r = 0; r < 4; ++r) {
    int b = tid + 256 * r;
    u32 c = (b < (int)NBLK) ? atomicAdd(&bcnt[b], 0u) : 0u;
    if (c > SLOT) atomicOr(&ovfs, 1u);
    u32 s = c > SLOT ? SLOT : c;
    if (s) {
      u32 base = atomicAdd(&ccnt, s);
      if (base + s > CAPL) atomicOr(&ovfs, 1u);
      for (u32 i = 0; i < s; ++i)
        if (base + i < CAPL)
          ckey[base + i] = atomicOr(&cand[(u32)b * SLOT + i], 0ull);
    }
  }
  __syncthreads();
  u32 count = ccnt > CAPL ? CAPL : ccnt;

  if (count < (u32)KTOP || ovfs) {
    // ---- rescue: exact one-block histogram rescan (never taken) ----
    for (int i = tid; i < 2048; i += 256) rhist[i] = 0u;
    __syncthreads();
    for (u32 qq = (u32)tid; qq < NQ; qq += 256u) {
      float4 oo = ((const float4*)obj)[qq];
      float o2[4] = {oo.x, oo.y, oo.z, oo.w};
      for (int k = 0; k < 4; ++k) {
        float so = sigm(o2[k]);
        u32 a = qq * 4u + (u32)k;
        const float4* cp = (const float4*)(cls + (size_t)a * 20u);
        for (int v = 0; v < 5; ++v) {
          float4 cv = cp[v];
          float cc[4] = {cv.x, cv.y, cv.z, cv.w};
          for (int j = 0; j < 4; ++j)
            atomicAdd(&rhist[__float_as_uint(so * sigm(cc[j])) >> 19], 1u);
        }
      }
    }
    __syncthreads();
    if (tid == 0) {
      u32 cum = 0; int b = 2047;
      for (; b >= 0; --b) { cum += rhist[b]; if (cum >= (u32)KTOP) break; }
      bstar_s = (b < 0) ? 0u : (u32)b;
    }
    __syncthreads();
    u32 rb = bstar_s;
    for (u32 qq = (u32)tid; qq < NQ; qq += 256u) {
      float4 oo = ((const float4*)obj)[qq];
      float o2[4] = {oo.x, oo.y, oo.z, oo.w};
      for (int k = 0; k < 4; ++k) {
        float so = sigm(o2[k]);
        u32 a = qq * 4u + (u32)k;
        const float4* cp = (const float4*)(cls + (size_t)a * 20u);
        for (int v = 0; v < 5; ++v) {
          float4 cv = cp[v];
          float cc[4] = {cv.x, cv.y, cv.z, cv.w};
          for (int j = 0; j < 4; ++j) {
            float sct = so * sigm(cc[j]);
            if ((__float_as_uint(sct) >> 19) >= rb) {
              u32 p = atomicAdd(&rcnt, 1u);
              u32 idx = a * 20u + (u32)(v * 4 + j);
              if (p < CAPL)
                ckey[p] = ((u64)__float_as_uint(sct) << 32) | (u64)(0xFFFFFFFFu - idx);
            }
          }
        }
      }
    }
    __syncthreads();
    count = rcnt > CAPL ? CAPL : rcnt;
  }

  // ---- fine histogram: bin=(bits>>14)-64512 exact+monotone on [0.5,1) ----
  for (u32 t = (u32)tid; t < count; t += 256u) {
    int bin = (int)((u32)(ckey[t] >> 32) >> 14) - 64512;
    bin = bin < 0 ? 0 : (bin > 511 ? 511 : bin);
    atomicAdd(&fhist[bin], 1u);
  }
  __syncthreads();

  // ---- bstar via wave-0 suffix scan ----
  if (tid < 64) {
    u32 b[8];
#pragma unroll
    for (int i = 0; i < 8; ++i) b[i] = fhist[lane * 8 + i];
    u32 seg = b[0] + b[1] + b[2] + b[3] + b[4] + b[5] + b[6] + b[7];
    u32 suf = seg;
#pragma unroll
    for (int d = 1; d < 64; d <<= 1) {
      u32 up = __shfl_down(suf, d);
      if (lane + d < 64) suf += up;
    }
    u64 mask = __ballot(suf >= (u32)KTOP);
    if (mask == 0ull) {
      if (lane == 0) { bstar_s = 0u; nsel_s = count; }
    } else {
      int lstar = 63 - __builtin_clzll(mask);
      int src = lstar < 63 ? lstar + 1 : 63;
      u32 cumAbove = __shfl(suf, src);
      if (lstar == 63) cumAbove = 0u;
      if (lane == lstar) {
        u32 cc2 = cumAbove; int found = 0; u32 ns = count; u32 bs = 0u;
#pragma unroll
        for (int i = 7; i >= 0; --i) {
          cc2 += b[i];
          if (!found && cc2 >= (u32)KTOP) { found = 1; bs = (u32)(lane * 8 + i); ns = cc2; }
        }
        bstar_s = bs; nsel_s = ns;
      }
    }
  }
  __syncthreads();
  const u32 bstar = bstar_s;
  const bool small = (nsel_s <= (u32)SELN);

  // ---- compact survivors (typical ~110) ----
  if (small) {
    for (u32 t = (u32)tid; t < count; t += 256u) {
      u64 k = ckey[t];
      int bin = (int)((u32)(k >> 32) >> 14) - 64512;
      bin = bin < 0 ? 0 : (bin > 511 ? 511 : bin);
      if ((u32)bin >= bstar) {
        u32 p = atomicAdd(&scnt, 1u);
        if (p < (u32)SELN) selk[p] = k;
      }
    }
  }
  __syncthreads();

  if (small) {
    u32 nn = scnt > (u32)SELN ? (u32)SELN : scnt;
    for (u32 t = (u32)tid; t < nn; t += 256u) {
      u64 k = selk[t];
      u32 rank = 0;
      for (u32 j = 0; j < nn; ++j) rank += (selk[j] > k) ? 1u : 0u;
      if (rank < (u32)KTOP) {
        sc[rank]  = __uint_as_float((u32)(k >> 32));
        sid[rank] = 0xFFFFFFFFu - (u32)(k & 0xFFFFFFFFull);
      }
    }
  } else {  // pathological fallback: exact rank over full LDS set (never taken)
    for (u32 t = (u32)tid; t < count; t += 256u) {
      u64 k = ckey[t];
      u32 rank = 0;
      for (u32 j = 0; j < count; ++j) rank += (ckey[j] > k) ? 1u : 0u;
      if (rank < (u32)KTOP) {
        sc[rank]  = __uint_as_float((u32)(k >> 32));
        sid[rank] = 0xFFFFFFFFu - (u32)(k & 0xFFFFFFFFull);
      }
    }
  }
  __syncthreads();

  // ---- decode top-100 ----
  if (tid < KTOP) {
    u32 idx = sid[tid];
    u32 a = idx / 20u, lab = idx % 20u;
    float4 r  = ((const float4*)reg)[a];
    float4 an = ((const float4*)anch)[a];
    float cx = (sigm(r.x) + an.x) * STRIDEF;
    float cy = (sigm(r.y) + an.y) * STRIDEF;
    float w  = fexp(r.z) * an.z;
    float h  = fexp(r.w) * an.w;
    float x1 = cx - 0.5f * w, y1 = cy - 0.5f * h;
    float x2 = cx + 0.5f * w, y2 = cy + 0.5f * h;
    bx[tid][0] = x1; bx[tid][1] = y1; bx[tid][2] = x2; bx[tid][3] = y2;
    float off = (float)lab * COFF;
    obF[tid] = make_float4(x1 + off, y1 + off, x2 + off, y2 + off);
  }
  __syncthreads();

  // ---- sup masks via ballot: one b128 LDS read per i, unroll 4 ----
  if (tid < 128) {
    int w = tid >> 6;
    int j = w * 64 + lane;
    bool jv = j < KTOP;
    float4 bj = jv ? obF[j] : make_float4(0.f, 0.f, 0.f, 0.f);
    float aj = (bj.z - bj.x) * (bj.w - bj.y);
#pragma unroll 4
    for (int i = 0; i < KTOP; ++i) {
      float4 bi = obF[i];
      float ai = (bi.z - bi.x) * (bi.w - bi.y);
      float xx1 = fmaxf(bi.x, bj.x), yy1 = fmaxf(bi.y, bj.y);
      float xx2 = fminf(bi.z, bj.z), yy2 = fminf(bi.w, bj.w);
      float ww = fmaxf(1e-10f, xx2 - xx1), hh = fmaxf(1e-10f, yy2 - yy1);
      float inter = ww * hh;
      float iou = inter / (ai + aj - inter);
      u64 m = __ballot(jv && (j > i) && (iou > NMS_T));
      if (lane == 0) { if (w == 0) suplo[i] = m; else suphi[i] = m; }
    }
  }
  __syncthreads();

  // ---- greedy NMS: rows in wave-0 registers, unrolled shfl, uniform ops ----
  if (tid < 64) {
    u64 rAlo = suplo[lane],                rAhi = suphi[lane];
    u64 rBlo = lane < 36 ? suplo[64 + lane] : 0ull;
    u64 rBhi = lane < 36 ? suphi[64 + lane] : 0ull;
    u64 k0 = __ballot(sc[lane] > CONF);
    u64 k1 = __ballot(lane < 36 && sc[64 + lane] > CONF);
#pragma unroll
    for (int i = 0; i < 64; ++i) {
      u64 s0 = __shfl(rAlo, i), s1 = __shfl(rAhi, i);
      if ((k0 >> i) & 1ull) { k0 &= ~s0; k1 &= ~s1; }
    }
#pragma unroll
    for (int i = 0; i < 36; ++i) {
      u64 s0 = __shfl(rBlo, i), s1 = __shfl(rBhi, i);
      if ((k1 >> i) & 1ull) { k0 &= ~s0; k1 &= ~s1; }
    }
    if (lane == 0) { keepm[0] = k0; keepm[1] = k1; }
  }
  __syncthreads();

  if (tid < KTOP) {
    out[tid * 4 + 0] = bx[tid][0];
    out[tid * 4 + 1] = bx[tid][1];
    out[tid * 4 + 2] = bx[tid][2];
    out[tid * 4 + 3] = bx[tid][3];
    out[400 + tid] = sc[tid];
    out[500 + tid] = (float)(sid[tid] % 20u);
    bool kp = (tid < 64) ? ((keepm[0] >> tid) & 1ull)
                         : ((keepm[1] >> (tid - 64)) & 1ull);
    out[600 + tid] = kp ? 1.0f : 0.0f;
  }
}

extern "C" void kernel_launch(void* const* d_in, const int* in_sizes, int n_in,
                              void* d_out, int out_size, void* d_ws, size_t ws_size,
                              hipStream_t stream) {
  (void)in_sizes; (void)n_in; (void)out_size; (void)ws_size;
  const float* obj  = (const float*)d_in[0];
  const float* cls  = (const float*)d_in[1];
  const float* reg  = (const float*)d_in[2];
  const float* anch = (const float*)d_in[3];
  float* out = (float*)d_out;

  u64* cand = (u64*)d_ws;
  u32* bcnt = (u32*)((char*)d_ws + (size_t)NBLK * SLOT * 8u);

  hipLaunchKernelGGL(k_fused, dim3(NBLK), dim3(256), 0, stream,
                     obj, cls, reg, anch, cand, bcnt, out);
}

// Round 11
// 39.971 us; speedup vs baseline: 4.1638x; 1.4951x over previous
//
#include <hip/hip_runtime.h>

// YOLOv2 post-process, ONE plain dispatch, hierarchical completion counters.
// score = sigm(obj)*sigm(cls), both < 1 => score>=T needs obj>=logit(T) AND
// cls>=logit(T); logit(0.86)=1.8153 > PRE_T=1.80 (prefilter skips ~97.4% of
// the 80MB cls read). 245 blocks x 1024 threads scan; candidates >= 0.86 are
// published to DETERMINISTIC per-block slots via device-scope atomicExch.
// Completion: two-level counter tree (8 padded per-group counters of ~31
// blocks + one final counter of 8) — avoids the 980-wide synchronized
// same-address atomic herd that cost r4/r10 ~64us (~65ns/op serialized).
// All counters self-wrap via atomicInc(p,N-1): stateless across graph replays.
// The completion-order-LAST block runs the wave-parallel tail with RMW reads
// (cross-XCD coherent): slot compaction -> fhist refine (wave suffix scan) ->
// exact rank (score desc, idx asc) -> decode -> ballot IoU masks ->
// register/shfl greedy NMS. Rescue (slot>64 / total<100 / total>2048): exact
// one-block rescan — never taken on this data, correctness backstop only.
// Outputs (float32 flat, 700): bboxes[400] | scores[100] | labels[100] | keep[100]

#define KTOP    100
#define CAPL    2048u          // LDS candidate cap (typical count ~1100)
#define SLOT    64u            // per-block slot cap (mean ~4.5, Poisson tail ~0)
#define NBLK    245u           // 245 * 1024 = 250880 = NQ exactly
#define SELN    512
#define NQ      250880u        // anchors/4
#define THRF    0.86f
#define PRE_T   1.80f          // sigm(1.80)=0.8581 < 0.86
#define CONF    0.01f
#define NMS_T   0.5f
#define STRIDEF 32.0f
#define COFF    1000000.0f

typedef unsigned long long u64;
typedef unsigned u32;

__device__ u32 g_cnt[8 * 32] = {};   // per-group counters, 128B apart (no line sharing)
__device__ u32 g_fin = 0;            // final counter (8 increments)

__device__ __forceinline__ float sigm(float x) {
  return __builtin_amdgcn_rcpf(1.0f + __builtin_amdgcn_exp2f(-1.442695040888963f * x));
}
__device__ __forceinline__ float fexp(float x) {
  return __builtin_amdgcn_exp2f(1.442695040888963f * x);
}

// ws: [0 .. 125440) cand u64[NBLK*SLOT]; [125440 .. 126420) bcnt u32[NBLK]

__global__ void __launch_bounds__(1024) k_fused(const float* __restrict__ obj,
    const float* __restrict__ cls, const float* __restrict__ reg,
    const float* __restrict__ anch, u64* __restrict__ cand,
    u32* __restrict__ bcnt, float* __restrict__ out) {
  __shared__ u64 lkey[SLOT];
  __shared__ u64 ckey[CAPL];                  // 16 KiB compacted candidates
  __shared__ u32 rhist[2048];                 // rescue only
  __shared__ u64 selk[SELN];
  __shared__ u32 fhist[512];
  __shared__ u32 lcnt, islast, ccnt, ovfs, scnt, bstar_s, nsel_s, rcnt;
  __shared__ float sc[KTOP];
  __shared__ u32 sid[KTOP];
  __shared__ float bx[KTOP][4];
  __shared__ float4 obF[KTOP];
  __shared__ u64 suplo[KTOP], suphi[KTOP], keepm[2];
  const int tid = threadIdx.x;
  const int lane = tid & 63;

  if (tid == 0) lcnt = 0u;
  __syncthreads();

  // ================= SCAN (all 245 blocks, 1024 threads) =================
  {
    u32 q = blockIdx.x * 1024u + (u32)tid;         // q < NQ (grid exact)
    float4 o4 = ((const float4*)obj)[q];
    float ov[4] = {o4.x, o4.y, o4.z, o4.w};
#pragma unroll
    for (int k = 0; k < 4; ++k) {
      if (ov[k] < PRE_T) continue;                 // 3.6% pass
      u32 a = q * 4u + (u32)k;
      float so = sigm(ov[k]);
      const float4* cp = (const float4*)(cls + (size_t)a * 20u);
      float4 c0 = cp[0], c1 = cp[1], c2 = cp[2], c3 = cp[3], c4 = cp[4];
      float cc[20] = {c0.x, c0.y, c0.z, c0.w, c1.x, c1.y, c1.z, c1.w,
                      c2.x, c2.y, c2.z, c2.w, c3.x, c3.y, c3.z, c3.w,
                      c4.x, c4.y, c4.z, c4.w};
#pragma unroll
      for (int j = 0; j < 20; ++j) {               // fully unrolled: static idx
        if (cc[j] >= PRE_T) {
          float s = so * sigm(cc[j]);
          if (s >= THRF) {
            u32 p = atomicAdd(&lcnt, 1u);          // LDS atomic only
            u32 idx = a * 20u + (u32)j;
            if (p < SLOT)
              lkey[p] = ((u64)__float_as_uint(s) << 32) | (u64)(0xFFFFFFFFu - idx);
          }
        }
      }
    }
    __syncthreads();
    // publish via device-scope RMW (coherent point)
    u32 n = lcnt > SLOT ? SLOT : lcnt;
    for (u32 t = (u32)tid; t < n; t += 1024u)
      atomicExch(&cand[blockIdx.x * SLOT + t], lkey[t]);
    if (tid == 0) atomicExch(&bcnt[blockIdx.x], lcnt);
    __syncthreads();                               // drains vmcnt: publishes complete
    if (tid == 0) {
      u32 c = blockIdx.x & 7u;                     // 245 = 5*31 + 3*30
      u32 grp = (c < 5u) ? 31u : 30u;
      u32 last = 0u;
      u32 old = atomicInc(&g_cnt[c * 32u], grp - 1u);   // wraps to 0 each call
      if (old == grp - 1u) {
        u32 f = atomicInc(&g_fin, 7u);             // wraps to 0 each call
        last = (f == 7u) ? 1u : 0u;
      }
      islast = last;
    }
    __syncthreads();
    if (!islast) return;
  }

  // ================= TAIL (completion-order-last block, 1024 threads) =================
  if (tid == 0) { ccnt = 0u; ovfs = 0u; rcnt = 0u; scnt = 0u; }
  if (tid < KTOP) { sc[tid] = 0.0f; sid[tid] = 0u; }
  if (tid < 512) fhist[tid] = 0u;
  __syncthreads();

  // ---- slot compaction into LDS via RMW reads (order-free; key = tie-break) ----
  if (tid < (int)NBLK) {
    u32 c = atomicAdd(&bcnt[tid], 0u);
    if (c > SLOT) atomicOr(&ovfs, 1u);
    u32 s = c > SLOT ? SLOT : c;
    if (s) {
      u32 base = atomicAdd(&ccnt, s);
      if (base + s > CAPL) atomicOr(&ovfs, 1u);
      for (u32 i = 0; i < s; ++i)
        if (base + i < CAPL)
          ckey[base + i] = atomicOr(&cand[(u32)tid * SLOT + i], 0ull);
    }
  }
  __syncthreads();
  u32 count = ccnt > CAPL ? CAPL : ccnt;

  if (count < (u32)KTOP || ovfs) {
    // ---- rescue: exact one-block histogram rescan (never taken) ----
    for (int i = tid; i < 2048; i += 1024) rhist[i] = 0u;
    __syncthreads();
    for (u32 qq = (u32)tid; qq < NQ; qq += 1024u) {
      float4 oo = ((const float4*)obj)[qq];
      float o2[4] = {oo.x, oo.y, oo.z, oo.w};
      for (int k = 0; k < 4; ++k) {
        float so = sigm(o2[k]);
        u32 a = qq * 4u + (u32)k;
        const float4* cp = (const float4*)(cls + (size_t)a * 20u);
        for (int v = 0; v < 5; ++v) {
          float4 cv = cp[v];
          float cc[4] = {cv.x, cv.y, cv.z, cv.w};
          for (int j = 0; j < 4; ++j)
            atomicAdd(&rhist[__float_as_uint(so * sigm(cc[j])) >> 19], 1u);
        }
      }
    }
    __syncthreads();
    if (tid == 0) {
      u32 cum = 0; int b = 2047;
      for (; b >= 0; --b) { cum += rhist[b]; if (cum >= (u32)KTOP) break; }
      bstar_s = (b < 0) ? 0u : (u32)b;
    }
    __syncthreads();
    u32 rb = bstar_s;
    for (u32 qq = (u32)tid; qq < NQ; qq += 1024u) {
      float4 oo = ((const float4*)obj)[qq];
      float o2[4] = {oo.x, oo.y, oo.z, oo.w};
      for (int k = 0; k < 4; ++k) {
        float so = sigm(o2[k]);
        u32 a = qq * 4u + (u32)k;
        const float4* cp = (const float4*)(cls + (size_t)a * 20u);
        for (int v = 0; v < 5; ++v) {
          float4 cv = cp[v];
          float cc[4] = {cv.x, cv.y, cv.z, cv.w};
          for (int j = 0; j < 4; ++j) {
            float sct = so * sigm(cc[j]);
            if ((__float_as_uint(sct) >> 19) >= rb) {
              u32 p = atomicAdd(&rcnt, 1u);
              u32 idx = a * 20u + (u32)(v * 4 + j);
              if (p < CAPL)
                ckey[p] = ((u64)__float_as_uint(sct) << 32) | (u64)(0xFFFFFFFFu - idx);
            }
          }
        }
      }
    }
    __syncthreads();
    count = rcnt > CAPL ? CAPL : rcnt;
  }

  // ---- fine histogram: bin=(bits>>14)-64512 exact+monotone on [0.5,1) ----
  for (u32 t = (u32)tid; t < count; t += 1024u) {
    int bin = (int)((u32)(ckey[t] >> 32) >> 14) - 64512;
    bin = bin < 0 ? 0 : (bin > 511 ? 511 : bin);
    atomicAdd(&fhist[bin], 1u);
  }
  __syncthreads();

  // ---- bstar via wave-0 suffix scan ----
  if (tid < 64) {
    u32 b[8];
#pragma unroll
    for (int i = 0; i < 8; ++i) b[i] = fhist[lane * 8 + i];
    u32 seg = b[0] + b[1] + b[2] + b[3] + b[4] + b[5] + b[6] + b[7];
    u32 suf = seg;
#pragma unroll
    for (int d = 1; d < 64; d <<= 1) {
      u32 up = __shfl_down(suf, d);
      if (lane + d < 64) suf += up;
    }
    u64 mask = __ballot(suf >= (u32)KTOP);
    if (mask == 0ull) {
      if (lane == 0) { bstar_s = 0u; nsel_s = count; }
    } else {
      int lstar = 63 - __builtin_clzll(mask);
      int src = lstar < 63 ? lstar + 1 : 63;
      u32 cumAbove = __shfl(suf, src);
      if (lstar == 63) cumAbove = 0u;
      if (lane == lstar) {
        u32 cc2 = cumAbove; int found = 0; u32 ns = count; u32 bs = 0u;
#pragma unroll
        for (int i = 7; i >= 0; --i) {
          cc2 += b[i];
          if (!found && cc2 >= (u32)KTOP) { found = 1; bs = (u32)(lane * 8 + i); ns = cc2; }
        }
        bstar_s = bs; nsel_s = ns;
      }
    }
  }
  __syncthreads();
  const u32 bstar = bstar_s;
  const bool small = (nsel_s <= (u32)SELN);

  // ---- compact survivors (typical ~110) ----
  if (small) {
    for (u32 t = (u32)tid; t < count; t += 1024u) {
      u64 k = ckey[t];
      int bin = (int)((u32)(k >> 32) >> 14) - 64512;
      bin = bin < 0 ? 0 : (bin > 511 ? 511 : bin);
      if ((u32)bin >= bstar) {
        u32 p = atomicAdd(&scnt, 1u);
        if (p < (u32)SELN) selk[p] = k;
      }
    }
  }
  __syncthreads();

  if (small) {
    u32 nn = scnt > (u32)SELN ? (u32)SELN : scnt;
    for (u32 t = (u32)tid; t < nn; t += 1024u) {
      u64 k = selk[t];
      u32 rank = 0;
      for (u32 j = 0; j < nn; ++j) rank += (selk[j] > k) ? 1u : 0u;
      if (rank < (u32)KTOP) {
        sc[rank]  = __uint_as_float((u32)(k >> 32));
        sid[rank] = 0xFFFFFFFFu - (u32)(k & 0xFFFFFFFFull);
      }
    }
  } else {  // pathological fallback: exact rank over full LDS set (never taken)
    for (u32 t = (u32)tid; t < count; t += 1024u) {
      u64 k = ckey[t];
      u32 rank = 0;
      for (u32 j = 0; j < count; ++j) rank += (ckey[j] > k) ? 1u : 0u;
      if (rank < (u32)KTOP) {
        sc[rank]  = __uint_as_float((u32)(k >> 32));
        sid[rank] = 0xFFFFFFFFu - (u32)(k & 0xFFFFFFFFull);
      }
    }
  }
  __syncthreads();

  // ---- decode top-100 ----
  if (tid < KTOP) {
    u32 idx = sid[tid];
    u32 a = idx / 20u, lab = idx % 20u;
    float4 r  = ((const float4*)reg)[a];
    float4 an = ((const float4*)anch)[a];
    float cx = (sigm(r.x) + an.x) * STRIDEF;
    float cy = (sigm(r.y) + an.y) * STRIDEF;
    float w  = fexp(r.z) * an.z;
    float h  = fexp(r.w) * an.w;
    float x1 = cx - 0.5f * w, y1 = cy - 0.5f * h;
    float x2 = cx + 0.5f * w, y2 = cy + 0.5f * h;
    bx[tid][0] = x1; bx[tid][1] = y1; bx[tid][2] = x2; bx[tid][3] = y2;
    float off = (float)lab * COFF;
    obF[tid] = make_float4(x1 + off, y1 + off, x2 + off, y2 + off);
  }
  __syncthreads();

  // ---- sup masks via ballot: one b128 LDS read per i, unroll 4 ----
  if (tid < 128) {
    int w = tid >> 6;
    int j = w * 64 + lane;
    bool jv = j < KTOP;
    float4 bj = jv ? obF[j] : make_float4(0.f, 0.f, 0.f, 0.f);
    float aj = (bj.z - bj.x) * (bj.w - bj.y);
#pragma unroll 4
    for (int i = 0; i < KTOP; ++i) {
      float4 bi = obF[i];
      float ai = (bi.z - bi.x) * (bi.w - bi.y);
      float xx1 = fmaxf(bi.x, bj.x), yy1 = fmaxf(bi.y, bj.y);
      float xx2 = fminf(bi.z, bj.z), yy2 = fminf(bi.w, bj.w);
      float ww = fmaxf(1e-10f, xx2 - xx1), hh = fmaxf(1e-10f, yy2 - yy1);
      float inter = ww * hh;
      float iou = inter / (ai + aj - inter);
      u64 m = __ballot(jv && (j > i) && (iou > NMS_T));
      if (lane == 0) { if (w == 0) suplo[i] = m; else suphi[i] = m; }
    }
  }
  __syncthreads();

  // ---- greedy NMS: rows in wave-0 registers, unrolled shfl, uniform ops ----
  if (tid < 64) {
    u64 rAlo = suplo[lane],                rAhi = suphi[lane];
    u64 rBlo = lane < 36 ? suplo[64 + lane] : 0ull;
    u64 rBhi = lane < 36 ? suphi[64 + lane] : 0ull;
    u64 k0 = __ballot(sc[lane] > CONF);
    u64 k1 = __ballot(lane < 36 && sc[64 + lane] > CONF);
#pragma unroll
    for (int i = 0; i < 64; ++i) {
      u64 s0 = __shfl(rAlo, i), s1 = __shfl(rAhi, i);
      if ((k0 >> i) & 1ull) { k0 &= ~s0; k1 &= ~s1; }
    }
#pragma unroll
    for (int i = 0; i < 36; ++i) {
      u64 s0 = __shfl(rBlo, i), s1 = __shfl(rBhi, i);
      if ((k1 >> i) & 1ull) { k0 &= ~s0; k1 &= ~s1; }
    }
    if (lane == 0) { keepm[0] = k0; keepm[1] = k1; }
  }
  __syncthreads();

  if (tid < KTOP) {
    out[tid * 4 + 0] = bx[tid][0];
    out[tid * 4 + 1] = bx[tid][1];
    out[tid * 4 + 2] = bx[tid][2];
    out[tid * 4 + 3] = bx[tid][3];
    out[400 + tid] = sc[tid];
    out[500 + tid] = (float)(sid[tid] % 20u);
    bool kp = (tid < 64) ? ((keepm[0] >> tid) & 1ull)
                         : ((keepm[1] >> (tid - 64)) & 1ull);
    out[600 + tid] = kp ? 1.0f : 0.0f;
  }
}

extern "C" void kernel_launch(void* const* d_in, const int* in_sizes, int n_in,
                              void* d_out, int out_size, void* d_ws, size_t ws_size,
                              hipStream_t stream) {
  (void)in_sizes; (void)n_in; (void)out_size; (void)ws_size;
  const float* obj  = (const float*)d_in[0];
  const float* cls  = (const float*)d_in[1];
  const float* reg  = (const float*)d_in[2];
  const float* anch = (const float*)d_in[3];
  float* out = (float*)d_out;

  u64* cand = (u64*)d_ws;
  u32* bcnt = (u32*)((char*)d_ws + (size_t)NBLK * SLOT * 8u);

  hipLaunchKernelGGL(k_fused, dim3(NBLK), dim3(1024), 0, stream,
                     obj, cls, reg, anch, cand, bcnt, out);
}

// Round 12
// 36.951 us; speedup vs baseline: 4.5041x; 1.0817x over previous
//
#include <hip/hip_runtime.h>

// YOLOv2 post-process, 2 dispatches, no memset, no global atomics. CHAMPION
// (r8: 38.5us; r11's fully-fused 1-dispatch variant measured 40.0us — the
// dispatch boundary provides cross-XCD coherence for free, cheaper than any
// in-kernel completion handoff we measured).
// score = sigm(obj)*sigm(cls), both < 1 => score>=T needs obj>=logit(T) AND
// cls>=logit(T); logit(0.86)=1.8153 > PRE_T=1.80 (prefilter skips ~97.4% of
// the 80MB cls read).
// k_scan: 980 blocks; float4 obj read; passing anchors do dense 80B cls gather;
//         candidates >= 0.86 land in DETERMINISTIC per-block slots
//         cand[blk*64..], bcnt[blk] written unconditionally (no init needed,
//         no stale state across replays).
// k_tail: 1 block x 1024 — prefix-sum slot compaction into LDS, fhist refine
//         (wave suffix scan), exact rank (score desc, idx asc), decode,
//         ballot IoU masks, register/shfl greedy NMS.
// Rescue (any slot>64 / total<100 / total>CAP): exact one-block rescan —
// never taken on this data, correctness backstop only.
// Outputs (float32 flat, 700): bboxes[400] | scores[100] | labels[100] | keep[100]

#define KTOP    100
#define CAP     4096u
#define SLOT    64u
#define NBLK    980u
#define SELN    512
#define NQ      250880u        // anchors/4; scan grid covers exactly
#define THRF    0.86f
#define PRE_T   1.80f          // sigm(1.80)=0.8581 < 0.86
#define CONF    0.01f
#define NMS_T   0.5f
#define STRIDEF 32.0f
#define COFF    1000000.0f

typedef unsigned long long u64;
typedef unsigned u32;

__device__ __forceinline__ float sigm(float x) {
  return __builtin_amdgcn_rcpf(1.0f + __builtin_amdgcn_exp2f(-1.442695040888963f * x));
}
__device__ __forceinline__ float fexp(float x) {
  return __builtin_amdgcn_exp2f(1.442695040888963f * x);
}

// ws: [0 .. 501760)        cand u64[NBLK*SLOT]
//     [501760 .. 505680)   bcnt u32[NBLK]

__global__ void __launch_bounds__(256) k_scan(const float* __restrict__ obj,
    const float* __restrict__ cls, u64* __restrict__ cand,
    u32* __restrict__ bcnt) {
  __shared__ u64 lkey[SLOT];
  __shared__ u32 lcnt;
  const int tid = threadIdx.x;
  if (tid == 0) lcnt = 0u;
  __syncthreads();

  u32 q = blockIdx.x * 256u + (u32)tid;            // q < NQ (grid exact)
  float4 o4 = ((const float4*)obj)[q];
  float ov[4] = {o4.x, o4.y, o4.z, o4.w};
#pragma unroll
  for (int k = 0; k < 4; ++k) {
    if (ov[k] < PRE_T) continue;                   // 3.6% pass
    u32 a = q * 4u + (u32)k;
    float so = sigm(ov[k]);
    const float4* cp = (const float4*)(cls + (size_t)a * 20u);
    float4 c0 = cp[0], c1 = cp[1], c2 = cp[2], c3 = cp[3], c4 = cp[4];
    float cc[20] = {c0.x, c0.y, c0.z, c0.w, c1.x, c1.y, c1.z, c1.w,
                    c2.x, c2.y, c2.z, c2.w, c3.x, c3.y, c3.z, c3.w,
                    c4.x, c4.y, c4.z, c4.w};
#pragma unroll
    for (int j = 0; j < 20; ++j) {                 // fully unrolled: static idx
      if (cc[j] >= PRE_T) {
        float s = so * sigm(cc[j]);
        if (s >= THRF) {
          u32 p = atomicAdd(&lcnt, 1u);            // LDS atomic only
          u32 idx = a * 20u + (u32)j;
          if (p < SLOT)
            lkey[p] = ((u64)__float_as_uint(s) << 32) | (u64)(0xFFFFFFFFu - idx);
        }
      }
    }
  }
  __syncthreads();
  u32 n = lcnt > SLOT ? SLOT : lcnt;
  for (u32 t = (u32)tid; t < n; t += 256u)
    cand[blockIdx.x * SLOT + t] = lkey[t];         // deterministic slot
  if (tid == 0) bcnt[blockIdx.x] = lcnt;           // uncapped: >SLOT => rescue
}

// ---- compaction + selection + decode + NMS (one block, 1024 threads) ----
__global__ void __launch_bounds__(1024) k_tail(const float* __restrict__ obj,
    const float* __restrict__ cls, const float* __restrict__ reg,
    const float* __restrict__ anch, const u64* __restrict__ cand,
    const u32* __restrict__ bcnt, float* __restrict__ out) {
  __shared__ u64 ckey[CAP];                   // 32 KiB compacted candidates
  __shared__ u32 rhist[2048];                 // rescue only
  __shared__ u64 selk[SELN];
  __shared__ u32 fhist[512];
  __shared__ u32 wsum[16];
  __shared__ u32 ovfs, scnt, bstar_s, nsel_s, rcnt;
  __shared__ float sc[KTOP];
  __shared__ u32 sid[KTOP];
  __shared__ float bx[KTOP][4];
  __shared__ float4 obF[KTOP];
  __shared__ u64 suplo[KTOP], suphi[KTOP], keepm[2];
  const int tid = threadIdx.x;
  const int lane = tid & 63;
  const int wid = tid >> 6;

  if (tid == 0) { ovfs = 0u; scnt = 0u; rcnt = 0u; }
  if (tid < KTOP) { sc[tid] = 0.0f; sid[tid] = 0u; }
  if (tid < 512) fhist[tid] = 0u;
  __syncthreads();

  // ---- per-block counts -> prefix sum (wave shfl + 16-partial scan) ----
  u32 c = (tid < (int)NBLK) ? bcnt[tid] : 0u;
  if (c > SLOT) atomicOr(&ovfs, 1u);
  u32 s = c > SLOT ? SLOT : c;
  u32 x = s;
#pragma unroll
  for (int d = 1; d < 64; d <<= 1) {
    u32 y = __shfl_up(x, d);
    if (lane >= d) x += y;
  }
  if (lane == 63) wsum[wid] = x;
  __syncthreads();
  if (wid == 0) {
    u32 w = (lane < 16) ? wsum[lane] : 0u;
#pragma unroll
    for (int d = 1; d < 16; d <<= 1) {
      u32 y = __shfl_up(w, d);
      if (lane >= d) w += y;
    }
    if (lane < 16) wsum[lane] = w;
  }
  __syncthreads();
  u32 base = (wid > 0 ? wsum[wid - 1] : 0u) + x - s;
  u32 total = wsum[15];
  u32 ovf = ovfs;

  if (total >= (u32)KTOP && total <= CAP && !ovf) {
    // ---- gather slots into LDS (typical ~1100 entries, ~0-3 per thread) ----
    for (u32 i = 0; i < s; ++i)
      ckey[base + i] = cand[(u32)tid * SLOT + i];
    __syncthreads();
  } else {
    // ---- rescue: exact one-block histogram rescan (never taken) ----
    for (int i = tid; i < 2048; i += 1024) rhist[i] = 0u;
    __syncthreads();
    for (u32 qq = (u32)tid; qq < NQ; qq += 1024u) {
      float4 oo = ((const float4*)obj)[qq];
      float o2[4] = {oo.x, oo.y, oo.z, oo.w};
      for (int k = 0; k < 4; ++k) {
        float so = sigm(o2[k]);
        u32 a = qq * 4u + (u32)k;
        const float4* cp = (const float4*)(cls + (size_t)a * 20u);
        for (int v = 0; v < 5; ++v) {
          float4 cv = cp[v];
          float cc[4] = {cv.x, cv.y, cv.z, cv.w};
          for (int j = 0; j < 4; ++j)
            atomicAdd(&rhist[__float_as_uint(so * sigm(cc[j])) >> 19], 1u);
        }
      }
    }
    __syncthreads();
    if (tid == 0) {
      u32 cum = 0; int b = 2047;
      for (; b >= 0; --b) { cum += rhist[b]; if (cum >= (u32)KTOP) break; }
      bstar_s = (b < 0) ? 0u : (u32)b;
    }
    __syncthreads();
    u32 rb = bstar_s;
    for (u32 qq = (u32)tid; qq < NQ; qq += 1024u) {
      float4 oo = ((const float4*)obj)[qq];
      float o2[4] = {oo.x, oo.y, oo.z, oo.w};
      for (int k = 0; k < 4; ++k) {
        float so = sigm(o2[k]);
        u32 a = qq * 4u + (u32)k;
        const float4* cp = (const float4*)(cls + (size_t)a * 20u);
        for (int v = 0; v < 5; ++v) {
          float4 cv = cp[v];
          float cc[4] = {cv.x, cv.y, cv.z, cv.w};
          for (int j = 0; j < 4; ++j) {
            float sct = so * sigm(cc[j]);
            if ((__float_as_uint(sct) >> 19) >= rb) {
              u32 p = atomicAdd(&rcnt, 1u);
              u32 idx = a * 20u + (u32)(v * 4 + j);
              if (p < CAP)
                ckey[p] = ((u64)__float_as_uint(sct) << 32) | (u64)(0xFFFFFFFFu - idx);
            }
          }
        }
      }
    }
    __syncthreads();
    total = rcnt > CAP ? CAP : rcnt;
  }
  const u32 count = total;

  // ---- fine histogram: bin=(bits>>14)-64512 exact+monotone on [0.5,1) ----
  for (u32 t = (u32)tid; t < count; t += 1024u) {
    int bin = (int)((u32)(ckey[t] >> 32) >> 14) - 64512;
    bin = bin < 0 ? 0 : (bin > 511 ? 511 : bin);
    atomicAdd(&fhist[bin], 1u);
  }
  __syncthreads();

  // ---- bstar via wave-0 suffix scan ----
  if (tid < 64) {
    u32 b[8];
#pragma unroll
    for (int i = 0; i < 8; ++i) b[i] = fhist[lane * 8 + i];
    u32 seg = b[0] + b[1] + b[2] + b[3] + b[4] + b[5] + b[6] + b[7];
    u32 suf = seg;
#pragma unroll
    for (int d = 1; d < 64; d <<= 1) {
      u32 up = __shfl_down(suf, d);
      if (lane + d < 64) suf += up;
    }
    u64 mask = __ballot(suf >= (u32)KTOP);
    if (mask == 0ull) {
      if (lane == 0) { bstar_s = 0u; nsel_s = count; }
    } else {
      int lstar = 63 - __builtin_clzll(mask);
      int src = lstar < 63 ? lstar + 1 : 63;
      u32 cumAbove = __shfl(suf, src);
      if (lstar == 63) cumAbove = 0u;
      if (lane == lstar) {
        u32 cc2 = cumAbove; int found = 0; u32 ns = count; u32 bs = 0u;
#pragma unroll
        for (int i = 7; i >= 0; --i) {
          cc2 += b[i];
          if (!found && cc2 >= (u32)KTOP) { found = 1; bs = (u32)(lane * 8 + i); ns = cc2; }
        }
        bstar_s = bs; nsel_s = ns;
      }
    }
  }
  __syncthreads();
  const u32 bstar = bstar_s;
  const bool small = (nsel_s <= (u32)SELN);

  // ---- compact survivors (typical ~110) ----
  if (small) {
    for (u32 t = (u32)tid; t < count; t += 1024u) {
      u64 k = ckey[t];
      int bin = (int)((u32)(k >> 32) >> 14) - 64512;
      bin = bin < 0 ? 0 : (bin > 511 ? 511 : bin);
      if ((u32)bin >= bstar) {
        u32 p = atomicAdd(&scnt, 1u);
        if (p < (u32)SELN) selk[p] = k;
      }
    }
  }
  __syncthreads();

  if (small) {
    u32 nn = scnt > (u32)SELN ? (u32)SELN : scnt;
    for (u32 t = (u32)tid; t < nn; t += 1024u) {
      u64 k = selk[t];
      u32 rank = 0;
      for (u32 j = 0; j < nn; ++j) rank += (selk[j] > k) ? 1u : 0u;
      if (rank < (u32)KTOP) {
        sc[rank]  = __uint_as_float((u32)(k >> 32));
        sid[rank] = 0xFFFFFFFFu - (u32)(k & 0xFFFFFFFFull);
      }
    }
  } else {  // pathological fallback: exact rank over full LDS set (never taken)
    for (u32 t = (u32)tid; t < count; t += 1024u) {
      u64 k = ckey[t];
      u32 rank = 0;
      for (u32 j = 0; j < count; ++j) rank += (ckey[j] > k) ? 1u : 0u;
      if (rank < (u32)KTOP) {
        sc[rank]  = __uint_as_float((u32)(k >> 32));
        sid[rank] = 0xFFFFFFFFu - (u32)(k & 0xFFFFFFFFull);
      }
    }
  }
  __syncthreads();

  // ---- decode top-100 ----
  if (tid < KTOP) {
    u32 idx = sid[tid];
    u32 a = idx / 20u, lab = idx % 20u;
    float4 r  = ((const float4*)reg)[a];
    float4 an = ((const float4*)anch)[a];
    float cx = (sigm(r.x) + an.x) * STRIDEF;
    float cy = (sigm(r.y) + an.y) * STRIDEF;
    float w  = fexp(r.z) * an.z;
    float h  = fexp(r.w) * an.w;
    float x1 = cx - 0.5f * w, y1 = cy - 0.5f * h;
    float x2 = cx + 0.5f * w, y2 = cy + 0.5f * h;
    bx[tid][0] = x1; bx[tid][1] = y1; bx[tid][2] = x2; bx[tid][3] = y2;
    float off = (float)lab * COFF;
    obF[tid] = make_float4(x1 + off, y1 + off, x2 + off, y2 + off);
  }
  __syncthreads();

  // ---- sup masks via ballot: one b128 LDS read per i, unroll 4 ----
  if (tid < 128) {
    int w = tid >> 6;
    int j = w * 64 + lane;
    bool jv = j < KTOP;
    float4 bj = jv ? obF[j] : make_float4(0.f, 0.f, 0.f, 0.f);
    float aj = (bj.z - bj.x) * (bj.w - bj.y);
#pragma unroll 4
    for (int i = 0; i < KTOP; ++i) {
      float4 bi = obF[i];
      float ai = (bi.z - bi.x) * (bi.w - bi.y);
      float xx1 = fmaxf(bi.x, bj.x), yy1 = fmaxf(bi.y, bj.y);
      float xx2 = fminf(bi.z, bj.z), yy2 = fminf(bi.w, bj.w);
      float ww = fmaxf(1e-10f, xx2 - xx1), hh = fmaxf(1e-10f, yy2 - yy1);
      float inter = ww * hh;
      float iou = inter / (ai + aj - inter);
      u64 m = __ballot(jv && (j > i) && (iou > NMS_T));
      if (lane == 0) { if (w == 0) suplo[i] = m; else suphi[i] = m; }
    }
  }
  __syncthreads();

  // ---- greedy NMS: rows in wave-0 registers, unrolled shfl, uniform ops ----
  if (tid < 64) {
    u64 rAlo = suplo[lane],                rAhi = suphi[lane];
    u64 rBlo = lane < 36 ? suplo[64 + lane] : 0ull;
    u64 rBhi = lane < 36 ? suphi[64 + lane] : 0ull;
    u64 k0 = __ballot(sc[lane] > CONF);
    u64 k1 = __ballot(lane < 36 && sc[64 + lane] > CONF);
#pragma unroll
    for (int i = 0; i < 64; ++i) {
      u64 s0 = __shfl(rAlo, i), s1 = __shfl(rAhi, i);
      if ((k0 >> i) & 1ull) { k0 &= ~s0; k1 &= ~s1; }
    }
#pragma unroll
    for (int i = 0; i < 36; ++i) {
      u64 s0 = __shfl(rBlo, i), s1 = __shfl(rBhi, i);
      if ((k1 >> i) & 1ull) { k0 &= ~s0; k1 &= ~s1; }
    }
    if (lane == 0) { keepm[0] = k0; keepm[1] = k1; }
  }
  __syncthreads();

  if (tid < KTOP) {
    out[tid * 4 + 0] = bx[tid][0];
    out[tid * 4 + 1] = bx[tid][1];
    out[tid * 4 + 2] = bx[tid][2];
    out[tid * 4 + 3] = bx[tid][3];
    out[400 + tid] = sc[tid];
    out[500 + tid] = (float)(sid[tid] % 20u);
    bool kp = (tid < 64) ? ((keepm[0] >> tid) & 1ull)
                         : ((keepm[1] >> (tid - 64)) & 1ull);
    out[600 + tid] = kp ? 1.0f : 0.0f;
  }
}

extern "C" void kernel_launch(void* const* d_in, const int* in_sizes, int n_in,
                              void* d_out, int out_size, void* d_ws, size_t ws_size,
                              hipStream_t stream) {
  (void)in_sizes; (void)n_in; (void)out_size; (void)ws_size;
  const float* obj  = (const float*)d_in[0];
  const float* cls  = (const float*)d_in[1];
  const float* reg  = (const float*)d_in[2];
  const float* anch = (const float*)d_in[3];
  float* out = (float*)d_out;

  u64* cand = (u64*)d_ws;
  u32* bcnt = (u32*)((char*)d_ws + (size_t)NBLK * SLOT * 8u);

  hipLaunchKernelGGL(k_scan, dim3(NBLK), dim3(256), 0, stream, obj, cls, cand, bcnt);
  hipLaunchKernelGGL(k_tail, dim3(1), dim3(1024), 0, stream,
                     obj, cls, reg, anch, cand, bcnt, out);
}